// Round 2
// baseline (390.885 us; speedup 1.0000x reference)
//
#include <hip/hip_runtime.h>
#include <math.h>

// Problem constants
#define BSZ 4
#define CCH 8192
#define HW  1024               // H*W = 32*32
#define DEMB 256
#define NPOS (BSZ*HW)          // 4096 spatial positions
#define QSIZE (BSZ*DEMB*HW)    // 1048576 floats (quantized)
#define KLOFF QSIZE            // kl scalar float offset in out
#define OHOFF (QSIZE+1)        // one_hot start (NOT 16B aligned)
#define OHSZ  ((size_t)BSZ*CCH*HW)  // 33554432

// Phase 1 (templated on channels-per-block):
// block = (b, chunk of CPB channels, all 1024 hw). 256 threads; thread t owns
// hw positions 4t..4t+3 (float4). Streams x/g rows contiguously; also writes
// the one_hot zeros for its rows via shifted-aligned float4 stores
// (out[QSIZE+n] covers one_hot[n-1..n+2]; k=0 store zeros the kl scalar).
template<int CPB>
__global__ __launch_bounds__(256) void vq_phase1(const float* __restrict__ x,
                                                 const float* __restrict__ g,
                                                 float* __restrict__ out,
                                                 float* __restrict__ ws) {
    constexpr int NCH = CCH / CPB;     // chunks per batch
    constexpr int P   = NPOS * NCH;    // partial entries
    int bid = blockIdx.x;
    int q = bid % NCH;
    int b = bid / NCH;
    int t = threadIdx.x;
    int c0 = q * CPB;
    size_t row0 = (size_t)(b * CCH + c0);
    size_t base = row0 * HW + 4 * t;

    float best[4]; int bidx[4]; float s[4], sx[4];
#pragma unroll
    for (int j = 0; j < 4; j++) { best[j] = -INFINITY; bidx[j] = 0; s[j] = 0.f; sx[j] = 0.f; }

    const float4 z4 = make_float4(0.f, 0.f, 0.f, 0.f);
#pragma unroll 4
    for (int c = 0; c < CPB; c++) {
        size_t a = base + (size_t)c * HW;
        float4 xv = *(const float4*)(x + a);
        float4 gv = *(const float4*)(g + a);
        *(float4*)(out + QSIZE + a) = z4;   // zero one_hot (shifted) + kl
        int cc = c0 + c;
        float xa[4] = {xv.x, xv.y, xv.z, xv.w};
        float ga[4] = {gv.x, gv.y, gv.z, gv.w};
#pragma unroll
        for (int j = 0; j < 4; j++) {
            float z = xa[j] + ga[j];
            if (z > best[j]) { best[j] = z; bidx[j] = cc; }
            s[j]  += __expf(xa[j]);
            sx[j] += xa[j];
        }
    }

    // the single element not covered by the shifted tiling: one_hot[last]
    if (b == BSZ - 1 && q == NCH - 1 && t == 255)
        out[QSIZE + OHSZ] = 0.f;

    // partials: [q][b][hw] for coalesced phase-2 reads
    int o = q * NPOS + b * HW + 4 * t;
    float* wbest = ws;
    int*   widx  = (int*)(ws + P);
    float* wsum  = ws + 2 * (size_t)P;
    float* wsx   = ws + 3 * (size_t)P;
    *(float4*)(wbest + o) = make_float4(best[0], best[1], best[2], best[3]);
    *(int4*)  (widx  + o) = make_int4(bidx[0], bidx[1], bidx[2], bidx[3]);
    *(float4*)(wsum  + o) = make_float4(s[0], s[1], s[2], s[3]);
    *(float4*)(wsx   + o) = make_float4(sx[0], sx[1], sx[2], sx[3]);
}

// Phase 2: merge NCH chunk-partials per position; write the 1.0s; kl atomic.
template<int CPB>
__global__ __launch_bounds__(256) void vq_phase2(float* __restrict__ out,
                                                 float* __restrict__ ws) {
    constexpr int NCH = CCH / CPB;
    constexpr int P   = NPOS * NCH;
    int pos = blockIdx.x * 256 + threadIdx.x;  // 0..4095
    const float* wbest = ws;
    const int*   widx  = (const int*)(ws + P);
    const float* wsum  = ws + 2 * (size_t)P;
    const float* wsx   = ws + 3 * (size_t)P;
    int*         fidx  = (int*)(ws + 4 * (size_t)P);

    float fb = -INFINITY; int fi = 0;
    float fs = 0.f, fsx = 0.f;
    for (int q = 0; q < NCH; q++) {
        int o = q * NPOS + pos;
        float v = wbest[o]; int ci = widx[o];
        if (v > fb || (v == fb && ci < fi)) { fb = v; fi = ci; }
        fs  += wsum[o];
        fsx += wsx[o];
    }
    fidx[pos] = fi;

    int b = pos >> 10;
    int hw = pos & (HW - 1);
    out[OHOFF + ((size_t)(b * CCH + fi)) * HW + hw] = 1.0f;

    float lse = __logf(fs);
    const float logt = -9.0109131783f;  // log(1/8192)
    float term = logt + lse - fsx * (1.0f / (float)CCH);

    for (int off = 32; off > 0; off >>= 1) term += __shfl_down(term, off, 64);
    __shared__ float wsuml[4];
    int lane = threadIdx.x & 63, wv = threadIdx.x >> 6;
    if (lane == 0) wsuml[wv] = term;
    __syncthreads();
    if (threadIdx.x == 0) {
        float tt = wsuml[0] + wsuml[1] + wsuml[2] + wsuml[3];
        atomicAdd(out + KLOFF, (0.25f / (float)BSZ) * tt);
    }
}

// Phase 3: quantized[b,d,hw] = emb[fidx[b,hw]][d]; float4 coalesced writes.
__global__ __launch_bounds__(256) void vq_phase3(const float* __restrict__ emb,
                                                 const int* __restrict__ fidx,
                                                 float* __restrict__ outq) {
    int u = blockIdx.x * 256 + threadIdx.x;   // < 262144
    int b = u >> 16;            // DEMB*HW/4 = 65536 groups per batch
    int r = u & 65535;
    int d = r >> 8;             // 256 float4-groups per d-row
    int h4 = (r & 255) * 4;
    int pos = (b << 10) + h4;
    float4 v;
    v.x = emb[fidx[pos + 0] * DEMB + d];
    v.y = emb[fidx[pos + 1] * DEMB + d];
    v.z = emb[fidx[pos + 2] * DEMB + d];
    v.w = emb[fidx[pos + 3] * DEMB + d];
    *(float4*)(outq + ((size_t)(b * DEMB + d) << 10) + h4) = v;
}

template<int CPB>
static void launch_all(const float* x, const float* emb, const float* g,
                       float* out, float* ws, hipStream_t stream) {
    constexpr int NCH = CCH / CPB;
    constexpr int P   = NPOS * NCH;
    vq_phase1<CPB><<<dim3(BSZ * NCH), dim3(256), 0, stream>>>(x, g, out, ws);
    vq_phase2<CPB><<<dim3(NPOS / 256), dim3(256), 0, stream>>>(out, ws);
    vq_phase3<<<dim3(QSIZE / 4 / 256), dim3(256), 0, stream>>>(
        emb, (const int*)(ws + 4 * (size_t)P), out);
}

extern "C" void kernel_launch(void* const* d_in, const int* in_sizes, int n_in,
                              void* d_out, int out_size, void* d_ws, size_t ws_size,
                              hipStream_t stream) {
    (void)in_sizes; (void)n_in; (void)out_size;
    const float* x   = (const float*)d_in[0];
    const float* emb = (const float*)d_in[1];
    const float* g   = (const float*)d_in[2];
    float* out = (float*)d_out;
    float* ws  = (float*)d_ws;

    // ws need (bytes): CPB=64 -> 16*524288+16384 ~= 8.4MB; 128 -> 4.2MB; 256 -> 2.1MB
    if (ws_size >= (size_t)16 * (NPOS * (CCH / 64)) + 4 * NPOS) {
        launch_all<64>(x, emb, g, out, ws, stream);        // 512 blocks, 2/CU
    } else if (ws_size >= (size_t)16 * (NPOS * (CCH / 128)) + 4 * NPOS) {
        launch_all<128>(x, emb, g, out, ws, stream);       // 256 blocks
    } else {
        launch_all<256>(x, emb, g, out, ws, stream);       // 128 blocks
    }
}

// Round 3
// 349.658 us; speedup vs baseline: 1.1179x; 1.1179x over previous
//
#include <hip/hip_runtime.h>
#include <math.h>

// Problem constants
#define BSZ 4
#define CCH 8192
#define HW  1024               // H*W = 32*32
#define DEMB 256
#define NPOS (BSZ*HW)          // 4096 spatial positions
#define QSIZE (BSZ*DEMB*HW)    // 1048576 floats (quantized)
#define KLOFF QSIZE            // kl scalar float offset in out
#define OHOFF (QSIZE+1)        // one_hot start (NOT 16B aligned)
#define OHSZ  ((size_t)BSZ*CCH*HW)  // 33554432

// Phase 1: block = (b, chunk of CPB channels, all 1024 hw). 256 threads;
// thread t owns hw positions 4t..4t+3 (float4). Streams x/g contiguously,
// fuses the one_hot zeroing via shifted-aligned float4 stores
// (out[QSIZE+n..n+3] covers kl/one_hot; c==0 store zeros the kl scalar).
template<int CPB>
__global__ __launch_bounds__(256) void vq_phase1(const float* __restrict__ x,
                                                 const float* __restrict__ g,
                                                 float* __restrict__ out,
                                                 float* __restrict__ ws) {
    constexpr int NCH = CCH / CPB;
    constexpr int P   = NPOS * NCH;
    int bid = blockIdx.x;
    int q = bid % NCH;
    int b = bid / NCH;
    int t = threadIdx.x;
    int c0 = q * CPB;
    size_t base = ((size_t)(b * CCH + c0)) * HW + 4 * t;

    float best[4]; int bidx[4]; float s[4], sx[4];
#pragma unroll
    for (int j = 0; j < 4; j++) { best[j] = -INFINITY; bidx[j] = 0; s[j] = 0.f; sx[j] = 0.f; }

    const float4 z4 = make_float4(0.f, 0.f, 0.f, 0.f);
#pragma unroll 4
    for (int c = 0; c < CPB; c++) {
        size_t a = base + (size_t)c * HW;
        float4 xv = *(const float4*)(x + a);
        float4 gv = *(const float4*)(g + a);
        *(float4*)(out + QSIZE + a) = z4;   // zero one_hot (shifted) + kl
        int cc = c0 + c;
        float xa[4] = {xv.x, xv.y, xv.z, xv.w};
        float ga[4] = {gv.x, gv.y, gv.z, gv.w};
#pragma unroll
        for (int j = 0; j < 4; j++) {
            float z = xa[j] + ga[j];
            if (z > best[j]) { best[j] = z; bidx[j] = cc; }
            s[j]  += __expf(xa[j]);
            sx[j] += xa[j];
        }
    }

    // single element not covered by the shifted tiling: one_hot[last]
    if (b == BSZ - 1 && q == NCH - 1 && t == 255)
        out[QSIZE + OHSZ] = 0.f;

    // partials laid out [q][pos] for coalesced phase-2 reads
    int o = q * NPOS + b * HW + 4 * t;
    float* wbest = ws;
    int*   widx  = (int*)(ws + (size_t)P);
    float* wsum  = ws + 2 * (size_t)P;
    float* wsx   = ws + 3 * (size_t)P;
    *(float4*)(wbest + o) = make_float4(best[0], best[1], best[2], best[3]);
    *(int4*)  (widx  + o) = make_int4(bidx[0], bidx[1], bidx[2], bidx[3]);
    *(float4*)(wsum  + o) = make_float4(s[0], s[1], s[2], s[3]);
    *(float4*)(wsx   + o) = make_float4(sx[0], sx[1], sx[2], sx[3]);
}

// Phase 2: grid NPOS/16 blocks x 256 threads. thread = (pl = pos-lane 0..15,
// qg = chunk-group 0..15). Each thread merges NCH/16 chunks (ascending q),
// LDS merge across the 16 groups (ascending), then 16 finalists per block
// write fidx + the one_hot 1.0 and block-reduce the KL term -> one atomic.
template<int CPB>
__global__ __launch_bounds__(256) void vq_phase2(float* __restrict__ out,
                                                 float* __restrict__ ws) {
    constexpr int NCH = CCH / CPB;
    constexpr int P   = NPOS * NCH;
    constexpr int QPT = NCH / 16;
    const float* wbest = ws;
    const int*   widx  = (const int*)(ws + (size_t)P);
    const float* wsum  = ws + 2 * (size_t)P;
    const float* wsx   = ws + 3 * (size_t)P;
    int*         fidx  = (int*)(ws + 4 * (size_t)P);

    int tid = threadIdx.x;
    int pl = tid & 15;
    int qg = tid >> 4;
    int pos0 = blockIdx.x * 16;
    int pos = pos0 + pl;

    float fb = -INFINITY; int fi = 0;
    float fs = 0.f, fsx = 0.f;
    for (int i = 0; i < QPT; i++) {
        int q = qg * QPT + i;
        int o = q * NPOS + pos;
        float v = wbest[o]; int ci = widx[o];
        if (v > fb || (v == fb && ci < fi)) { fb = v; fi = ci; }
        fs  += wsum[o];
        fsx += wsx[o];
    }

    __shared__ float l_b [16][17];
    __shared__ int   l_i [16][17];
    __shared__ float l_s [16][17];
    __shared__ float l_sx[16][17];
    __shared__ float tsum[16];
    l_b [qg][pl] = fb;
    l_i [qg][pl] = fi;
    l_s [qg][pl] = fs;
    l_sx[qg][pl] = fsx;
    __syncthreads();

    if (tid < 16) {
        int p = tid;
        float mb = l_b[0][p]; int mi = l_i[0][p];
        float ms = l_s[0][p], msx = l_sx[0][p];
        for (int qq = 1; qq < 16; qq++) {
            float v = l_b[qq][p]; int ci = l_i[qq][p];
            if (v > mb || (v == mb && ci < mi)) { mb = v; mi = ci; }
            ms  += l_s[qq][p];
            msx += l_sx[qq][p];
        }
        int mypos = pos0 + p;
        fidx[mypos] = mi;
        int b = mypos >> 10;
        int hw = mypos & (HW - 1);
        out[OHOFF + ((size_t)(b * CCH + mi)) * HW + hw] = 1.0f;

        const float logt = -9.0109131783f;  // log(1/8192)
        tsum[p] = logt + __logf(ms) - msx * (1.0f / (float)CCH);
    }
    __syncthreads();
    if (tid == 0) {
        float tt = 0.f;
        for (int p = 0; p < 16; p++) tt += tsum[p];
        atomicAdd(out + KLOFF, (0.25f / (float)BSZ) * tt);
    }
}

// Phase 3: quantized[b,d,hw] = emb[fidx[b,hw]][d]; float4 coalesced writes,
// gathers hit L2/L3 (emb = 8 MB).
__global__ __launch_bounds__(256) void vq_phase3(const float* __restrict__ emb,
                                                 const int* __restrict__ fidx,
                                                 float* __restrict__ outq) {
    int u = blockIdx.x * 256 + threadIdx.x;   // < 262144
    int b = u >> 16;
    int r = u & 65535;
    int d = r >> 8;
    int h4 = (r & 255) * 4;
    int pos = (b << 10) + h4;
    float4 v;
    v.x = emb[fidx[pos + 0] * DEMB + d];
    v.y = emb[fidx[pos + 1] * DEMB + d];
    v.z = emb[fidx[pos + 2] * DEMB + d];
    v.w = emb[fidx[pos + 3] * DEMB + d];
    *(float4*)(outq + ((size_t)(b * DEMB + d) << 10) + h4) = v;
}

template<int CPB>
static void launch_all(const float* x, const float* emb, const float* g,
                       float* out, float* ws, hipStream_t stream) {
    constexpr int NCH = CCH / CPB;
    constexpr int P   = NPOS * NCH;
    vq_phase1<CPB><<<dim3(BSZ * NCH), dim3(256), 0, stream>>>(x, g, out, ws);
    vq_phase2<CPB><<<dim3(NPOS / 16), dim3(256), 0, stream>>>(out, ws);
    vq_phase3<<<dim3(QSIZE / 4 / 256), dim3(256), 0, stream>>>(
        emb, (const int*)(ws + 4 * (size_t)P), out);
}

extern "C" void kernel_launch(void* const* d_in, const int* in_sizes, int n_in,
                              void* d_out, int out_size, void* d_ws, size_t ws_size,
                              hipStream_t stream) {
    (void)in_sizes; (void)n_in; (void)out_size;
    const float* x   = (const float*)d_in[0];
    const float* emb = (const float*)d_in[1];
    const float* g   = (const float*)d_in[2];
    float* out = (float*)d_out;
    float* ws  = (float*)d_ws;

    // ws bytes needed: CPB=32 -> 16*(4096*256)+16K ~= 16.8MB; CPB=64 ~= 8.4MB
    if (ws_size >= (size_t)16 * ((size_t)NPOS * (CCH / 32)) + 4 * NPOS) {
        launch_all<32>(x, emb, g, out, ws, stream);   // 1024 blocks, 50% occ
    } else {
        launch_all<64>(x, emb, g, out, ws, stream);   // 512 blocks, 25% occ
    }
}

// Round 5
// 335.874 us; speedup vs baseline: 1.1638x; 1.0410x over previous
//
#include <hip/hip_runtime.h>
#include <math.h>

// Problem constants
#define BSZ 4
#define CCH 8192
#define HW  1024               // H*W = 32*32
#define DEMB 256
#define NPOS (BSZ*HW)          // 4096 spatial positions
#define QSIZE (BSZ*DEMB*HW)    // 1048576 floats (quantized)
#define KLOFF QSIZE            // kl scalar float offset in out
#define OHOFF (QSIZE+1)        // one_hot start (NOT 16B aligned)
#define OHSZ  ((size_t)BSZ*CCH*HW)  // 33554432

typedef float vf4 __attribute__((ext_vector_type(4)));

// Phase 1: block = (b, chunk of CPB channels, all 1024 hw). 256 threads;
// thread t owns hw positions 4t..4t+3 (vf4). Streams x/g contiguously
// with batched (unroll-8) non-temporal loads for max loads-in-flight, and
// fuses the one_hot zeroing via shifted-aligned NT vf4 stores
// (out[QSIZE+n..n+3]; the c==0,t==0 store also zeros the kl scalar).
template<int CPB>
__global__ __launch_bounds__(256) void vq_phase1(const float* __restrict__ x,
                                                 const float* __restrict__ g,
                                                 float* __restrict__ out,
                                                 float* __restrict__ ws) {
    constexpr int NCH = CCH / CPB;
    constexpr int P   = NPOS * NCH;
    constexpr int UN  = 8;
    int bid = blockIdx.x;
    int q = bid % NCH;
    int b = bid / NCH;
    int t = threadIdx.x;
    int c0 = q * CPB;
    size_t base = ((size_t)(b * CCH + c0)) * HW + 4 * t;

    float best[4]; int bidx[4]; float s[4], sx[4];
#pragma unroll
    for (int j = 0; j < 4; j++) { best[j] = -INFINITY; bidx[j] = 0; s[j] = 0.f; sx[j] = 0.f; }

    const vf4 z4 = (vf4)(0.f);
    for (int cg = 0; cg < CPB / UN; cg++) {
        size_t a0 = base + (size_t)cg * UN * HW;
        vf4 xv[UN], gv[UN];
#pragma unroll
        for (int u = 0; u < UN; u++)
            xv[u] = __builtin_nontemporal_load((const vf4*)(x + a0 + (size_t)u * HW));
#pragma unroll
        for (int u = 0; u < UN; u++)
            gv[u] = __builtin_nontemporal_load((const vf4*)(g + a0 + (size_t)u * HW));
#pragma unroll
        for (int u = 0; u < UN; u++)
            __builtin_nontemporal_store(z4, (vf4*)(out + QSIZE + a0 + (size_t)u * HW));
#pragma unroll
        for (int u = 0; u < UN; u++) {
            int cc = c0 + cg * UN + u;
#pragma unroll
            for (int j = 0; j < 4; j++) {
                float xa = xv[u][j];
                float z = xa + gv[u][j];
                if (z > best[j]) { best[j] = z; bidx[j] = cc; }
                s[j]  += __expf(xa);
                sx[j] += xa;
            }
        }
    }

    // single element not covered by the shifted tiling: one_hot[last]
    if (b == BSZ - 1 && q == NCH - 1 && t == 255)
        out[QSIZE + OHSZ] = 0.f;

    // partials laid out [q][pos] for coalesced phase-2 reads
    int o = q * NPOS + b * HW + 4 * t;
    float* wbest = ws;
    int*   widx  = (int*)(ws + (size_t)P);
    float* wsum  = ws + 2 * (size_t)P;
    float* wsx   = ws + 3 * (size_t)P;
    *(float4*)(wbest + o) = make_float4(best[0], best[1], best[2], best[3]);
    *(int4*)  (widx  + o) = make_int4(bidx[0], bidx[1], bidx[2], bidx[3]);
    *(float4*)(wsum  + o) = make_float4(s[0], s[1], s[2], s[3]);
    *(float4*)(wsx   + o) = make_float4(sx[0], sx[1], sx[2], sx[3]);
}

// Phase 2: grid NPOS/16 blocks x 256 threads. thread = (pl = pos-lane 0..15,
// qg = chunk-group 0..15). Each thread merges NCH/16 chunks (ascending q),
// LDS merge across the 16 groups (ascending), then 16 finalists per block
// write fidx + the one_hot 1.0 and block-reduce the KL term -> one atomic.
template<int CPB>
__global__ __launch_bounds__(256) void vq_phase2(float* __restrict__ out,
                                                 float* __restrict__ ws) {
    constexpr int NCH = CCH / CPB;
    constexpr int P   = NPOS * NCH;
    constexpr int QPT = NCH / 16;
    const float* wbest = ws;
    const int*   widx  = (const int*)(ws + (size_t)P);
    const float* wsum  = ws + 2 * (size_t)P;
    const float* wsx   = ws + 3 * (size_t)P;
    int*         fidx  = (int*)(ws + 4 * (size_t)P);

    int tid = threadIdx.x;
    int pl = tid & 15;
    int qg = tid >> 4;
    int pos0 = blockIdx.x * 16;
    int pos = pos0 + pl;

    float fb = -INFINITY; int fi = 0;
    float fs = 0.f, fsx = 0.f;
    for (int i = 0; i < QPT; i++) {
        int q = qg * QPT + i;
        int o = q * NPOS + pos;
        float v = wbest[o]; int ci = widx[o];
        if (v > fb || (v == fb && ci < fi)) { fb = v; fi = ci; }
        fs  += wsum[o];
        fsx += wsx[o];
    }

    __shared__ float l_b [16][17];
    __shared__ int   l_i [16][17];
    __shared__ float l_s [16][17];
    __shared__ float l_sx[16][17];
    __shared__ float tsum[16];
    l_b [qg][pl] = fb;
    l_i [qg][pl] = fi;
    l_s [qg][pl] = fs;
    l_sx[qg][pl] = fsx;
    __syncthreads();

    if (tid < 16) {
        int p = tid;
        float mb = l_b[0][p]; int mi = l_i[0][p];
        float ms = l_s[0][p], msx = l_sx[0][p];
        for (int qq = 1; qq < 16; qq++) {
            float v = l_b[qq][p]; int ci = l_i[qq][p];
            if (v > mb || (v == mb && ci < mi)) { mb = v; mi = ci; }
            ms  += l_s[qq][p];
            msx += l_sx[qq][p];
        }
        int mypos = pos0 + p;
        fidx[mypos] = mi;
        int b = mypos >> 10;
        int hw = mypos & (HW - 1);
        out[OHOFF + ((size_t)(b * CCH + mi)) * HW + hw] = 1.0f;

        const float logt = -9.0109131783f;  // log(1/8192)
        tsum[p] = logt + __logf(ms) - msx * (1.0f / (float)CCH);
    }
    __syncthreads();
    if (tid == 0) {
        float tt = 0.f;
        for (int p = 0; p < 16; p++) tt += tsum[p];
        atomicAdd(out + KLOFF, (0.25f / (float)BSZ) * tt);
    }
}

// Phase 3: quantized[b,d,hw] = emb[fidx[b,hw]][d]; float4 coalesced writes,
// gathers hit L2/L3 (emb = 8 MB).
__global__ __launch_bounds__(256) void vq_phase3(const float* __restrict__ emb,
                                                 const int* __restrict__ fidx,
                                                 float* __restrict__ outq) {
    int u = blockIdx.x * 256 + threadIdx.x;   // < 262144
    int b = u >> 16;
    int r = u & 65535;
    int d = r >> 8;
    int h4 = (r & 255) * 4;
    int pos = (b << 10) + h4;
    float4 v;
    v.x = emb[fidx[pos + 0] * DEMB + d];
    v.y = emb[fidx[pos + 1] * DEMB + d];
    v.z = emb[fidx[pos + 2] * DEMB + d];
    v.w = emb[fidx[pos + 3] * DEMB + d];
    *(float4*)(outq + ((size_t)(b * DEMB + d) << 10) + h4) = v;
}

template<int CPB>
static void launch_all(const float* x, const float* emb, const float* g,
                       float* out, float* ws, hipStream_t stream) {
    constexpr int NCH = CCH / CPB;
    constexpr int P   = NPOS * NCH;
    vq_phase1<CPB><<<dim3(BSZ * NCH), dim3(256), 0, stream>>>(x, g, out, ws);
    vq_phase2<CPB><<<dim3(NPOS / 16), dim3(256), 0, stream>>>(out, ws);
    vq_phase3<<<dim3(QSIZE / 4 / 256), dim3(256), 0, stream>>>(
        emb, (const int*)(ws + 4 * (size_t)P), out);
}

extern "C" void kernel_launch(void* const* d_in, const int* in_sizes, int n_in,
                              void* d_out, int out_size, void* d_ws, size_t ws_size,
                              hipStream_t stream) {
    (void)in_sizes; (void)n_in; (void)out_size;
    const float* x   = (const float*)d_in[0];
    const float* emb = (const float*)d_in[1];
    const float* g   = (const float*)d_in[2];
    float* out = (float*)d_out;
    float* ws  = (float*)d_ws;

    // ws bytes needed: CPB=32 -> 16*(4096*256)+16K ~= 16.8MB; CPB=64 ~= 8.4MB
    if (ws_size >= (size_t)16 * ((size_t)NPOS * (CCH / 32)) + 4 * NPOS) {
        launch_all<32>(x, emb, g, out, ws, stream);   // 1024 blocks
    } else {
        launch_all<64>(x, emb, g, out, ws, stream);   // 512 blocks
    }
}

// Round 6
// 325.039 us; speedup vs baseline: 1.2026x; 1.0333x over previous
//
#include <hip/hip_runtime.h>
#include <math.h>

// Problem constants
#define BSZ 4
#define CCH 8192
#define HW  1024               // H*W = 32*32
#define DEMB 256
#define NPOS (BSZ*HW)          // 4096 spatial positions
#define QSIZE (BSZ*DEMB*HW)    // 1048576 floats (quantized)
#define KLOFF QSIZE            // kl scalar float offset in out
#define OHOFF (QSIZE+1)        // one_hot start (NOT 16B aligned)
#define OHSZ  ((size_t)BSZ*CCH*HW)  // 33554432

typedef float vf4 __attribute__((ext_vector_type(4)));

// Phase 1: block = (b, chunk of CPB channels, all 1024 hw). 256 threads;
// thread t owns hw positions 4t..4t+3 (vf4). Streams x/g contiguously with
// batched (UN=16) non-temporal loads for deep memory pipelining, and fuses
// the one_hot zeroing via shifted-aligned NT vf4 stores
// (out[QSIZE+n..n+3]; the c==0,t==0 store also zeros the kl scalar).
template<int CPB>
__global__ __launch_bounds__(256) void vq_phase1(const float* __restrict__ x,
                                                 const float* __restrict__ g,
                                                 float* __restrict__ out,
                                                 float* __restrict__ ws) {
    constexpr int NCH = CCH / CPB;
    constexpr int P   = NPOS * NCH;
    constexpr int UN  = 16;
    int bid = blockIdx.x;
    int q = bid % NCH;
    int b = bid / NCH;
    int t = threadIdx.x;
    int c0 = q * CPB;
    size_t base = ((size_t)(b * CCH + c0)) * HW + 4 * t;

    float best[4]; int bidx[4]; float s[4], sx[4];
#pragma unroll
    for (int j = 0; j < 4; j++) { best[j] = -INFINITY; bidx[j] = 0; s[j] = 0.f; sx[j] = 0.f; }

    const vf4 z4 = (vf4)(0.f);
    for (int cg = 0; cg < CPB / UN; cg++) {
        size_t a0 = base + (size_t)cg * UN * HW;
        vf4 xv[UN], gv[UN];
#pragma unroll
        for (int u = 0; u < UN; u++)
            xv[u] = __builtin_nontemporal_load((const vf4*)(x + a0 + (size_t)u * HW));
#pragma unroll
        for (int u = 0; u < UN; u++)
            gv[u] = __builtin_nontemporal_load((const vf4*)(g + a0 + (size_t)u * HW));
#pragma unroll
        for (int u = 0; u < UN; u++)
            __builtin_nontemporal_store(z4, (vf4*)(out + QSIZE + a0 + (size_t)u * HW));
#pragma unroll
        for (int u = 0; u < UN; u++) {
            int cc = c0 + cg * UN + u;
#pragma unroll
            for (int j = 0; j < 4; j++) {
                float xa = xv[u][j];
                float z = xa + gv[u][j];
                if (z > best[j]) { best[j] = z; bidx[j] = cc; }
                s[j]  += __expf(xa);
                sx[j] += xa;
            }
        }
    }

    // single element not covered by the shifted tiling: one_hot[last]
    if (b == BSZ - 1 && q == NCH - 1 && t == 255)
        out[QSIZE + OHSZ] = 0.f;

    // partials laid out [q][pos] for coalesced phase-2 reads
    int o = q * NPOS + b * HW + 4 * t;
    float* wbest = ws;
    int*   widx  = (int*)(ws + (size_t)P);
    float* wsum  = ws + 2 * (size_t)P;
    float* wsx   = ws + 3 * (size_t)P;
    *(float4*)(wbest + o) = make_float4(best[0], best[1], best[2], best[3]);
    *(int4*)  (widx  + o) = make_int4(bidx[0], bidx[1], bidx[2], bidx[3]);
    *(float4*)(wsum  + o) = make_float4(s[0], s[1], s[2], s[3]);
    *(float4*)(wsx   + o) = make_float4(sx[0], sx[1], sx[2], sx[3]);
}

// Phase 2 (fused finalize): grid NPOS/16 blocks x 256 threads.
// (a) merge NCH chunk-partials per position (thread = pl 0..15 x qg 0..15,
//     LDS merge), (b) write one_hot 1.0s + KL atomic, (c) load the 16
//     selected emb rows coalesced into LDS, transpose, and write the
//     quantized tile with per-thread 64B float4 runs.
template<int CPB>
__global__ __launch_bounds__(256) void vq_phase2(const float* __restrict__ emb,
                                                 float* __restrict__ out,
                                                 float* __restrict__ ws) {
    constexpr int NCH = CCH / CPB;
    constexpr int P   = NPOS * NCH;
    constexpr int QPT = NCH / 16;
    constexpr int TP  = 272;           // tile pitch (256+16)
    const float* wbest = ws;
    const int*   widx  = (const int*)(ws + (size_t)P);
    const float* wsum  = ws + 2 * (size_t)P;
    const float* wsx   = ws + 3 * (size_t)P;

    int tid = threadIdx.x;
    int pl = tid & 15;
    int qg = tid >> 4;
    int pos0 = blockIdx.x * 16;
    int pos = pos0 + pl;

    float fb = -INFINITY; int fi = 0;
    float fs = 0.f, fsx = 0.f;
    for (int i = 0; i < QPT; i++) {
        int q = qg * QPT + i;
        int o = q * NPOS + pos;
        float v = wbest[o]; int ci = widx[o];
        if (v > fb || (v == fb && ci < fi)) { fb = v; fi = ci; }
        fs  += wsum[o];
        fsx += wsx[o];
    }

    __shared__ float l_b [16][17];
    __shared__ int   l_i [16][17];
    __shared__ float l_s [16][17];
    __shared__ float l_sx[16][17];
    __shared__ float tsum[16];
    __shared__ int   smi[16];
    __shared__ float tile[16 * TP];
    l_b [qg][pl] = fb;
    l_i [qg][pl] = fi;
    l_s [qg][pl] = fs;
    l_sx[qg][pl] = fsx;
    __syncthreads();

    if (tid < 16) {
        int p = tid;
        float mb = l_b[0][p]; int mi = l_i[0][p];
        float ms = l_s[0][p], msx = l_sx[0][p];
        for (int qq = 1; qq < 16; qq++) {
            float v = l_b[qq][p]; int ci = l_i[qq][p];
            if (v > mb || (v == mb && ci < mi)) { mb = v; mi = ci; }
            ms  += l_s[qq][p];
            msx += l_sx[qq][p];
        }
        int mypos = pos0 + p;
        smi[p] = mi;
        int bb = mypos >> 10;
        int hw = mypos & (HW - 1);
        out[OHOFF + ((size_t)(bb * CCH + mi)) * HW + hw] = 1.0f;

        const float logt = -9.0109131783f;  // log(1/8192)
        tsum[p] = logt + __logf(ms) - msx * (1.0f / (float)CCH);
    }
    __syncthreads();
    if (tid == 0) {
        float tt = 0.f;
        for (int p = 0; p < 16; p++) tt += tsum[p];
        atomicAdd(out + KLOFF, (0.25f / (float)BSZ) * tt);
    }

    // (c) gather emb rows -> LDS (coalesced float4 loads, 4 rows per pass)
    int rr = tid >> 6;          // 0..3
    int c4 = (tid & 63) * 4;    // 0..252
#pragma unroll
    for (int rep = 0; rep < 4; rep++) {
        int r = rep * 4 + rr;
        float4 v = *(const float4*)(emb + (size_t)smi[r] * DEMB + c4);
        *(float4*)(tile + r * TP + c4) = v;
    }
    __syncthreads();

    // write quantized: thread d=tid owns a 64B run (16 hw) per 4-row group
    int b = pos0 >> 10;
    int hw0 = pos0 & (HW - 1);
    int d = tid;
    size_t obase = (((size_t)(b * DEMB + d)) << 10) + hw0;
#pragma unroll
    for (int k = 0; k < 4; k++) {
        float4 v;
        v.x = tile[(4 * k + 0) * TP + d];
        v.y = tile[(4 * k + 1) * TP + d];
        v.z = tile[(4 * k + 2) * TP + d];
        v.w = tile[(4 * k + 3) * TP + d];
        *(float4*)(out + obase + 4 * k) = v;
    }
}

template<int CPB>
static void launch_all(const float* x, const float* emb, const float* g,
                       float* out, float* ws, hipStream_t stream) {
    constexpr int NCH = CCH / CPB;
    vq_phase1<CPB><<<dim3(BSZ * NCH), dim3(256), 0, stream>>>(x, g, out, ws);
    vq_phase2<CPB><<<dim3(NPOS / 16), dim3(256), 0, stream>>>(emb, out, ws);
}

extern "C" void kernel_launch(void* const* d_in, const int* in_sizes, int n_in,
                              void* d_out, int out_size, void* d_ws, size_t ws_size,
                              hipStream_t stream) {
    (void)in_sizes; (void)n_in; (void)out_size;
    const float* x   = (const float*)d_in[0];
    const float* emb = (const float*)d_in[1];
    const float* g   = (const float*)d_in[2];
    float* out = (float*)d_out;
    float* ws  = (float*)d_ws;

    // ws bytes needed: CPB=32 -> 16*(4096*256) ~= 16.8MB; CPB=64 ~= 8.4MB
    if (ws_size >= (size_t)16 * ((size_t)NPOS * (CCH / 32))) {
        launch_all<32>(x, emb, g, out, ws, stream);   // 1024 blocks
    } else {
        launch_all<64>(x, emb, g, out, ws, stream);   // 512 blocks
    }
}